// Round 3
// baseline (277.717 us; speedup 1.0000x reference)
//
#include <hip/hip_runtime.h>

#define NH   8
#define NPTS 4
#define BB   8
#define CCH  256
#define HH   64
#define WW   64
#define NPIX 4096   // H*W
#define DH   32     // C/NH

// ---------------------------------------------------------------------------
// Kernel A: ow = q @ W_off + b_off, softmax over points, emit per-sample
// (xpix, ypix, weight) as float4.  Block = 64 pixels, 256 threads.
// q read directly from global (coalesced, no reuse); only W_off staged.
// ---------------------------------------------------------------------------
__global__ __launch_bounds__(256)
void kA_offsets(const float* __restrict__ query, const float* __restrict__ W_off,
                const float* __restrict__ b_off, float4* __restrict__ coords)
{
    __shared__ float w_lds[64][96];   // [k][j]

    const int t  = threadIdx.x;
    const int g0 = blockIdx.x * 64;        // global pixel base (b*NPIX + n)
    const int b  = g0 >> 12;
    const int n0 = g0 & (NPIX - 1);

    const int px = t & 63;
    const int jg = t >> 6;                 // wave id 0..3
    const int j0 = jg * 24;

    const float* qcol = query + (size_t)b * CCH * NPIX + n0 + px;

    float acc[24];
#pragma unroll
    for (int i = 0; i < 24; ++i) acc[i] = 0.f;

    for (int kc = 0; kc < CCH; kc += 64) {
        // stage W_off tile: w_lds[k][j], 64 rows x 96 cols (1536 float4)
#pragma unroll
        for (int ii = 0; ii < 6; ++ii) {
            int i4 = t + ii * 256;
            int k  = i4 / 24;
            int j4 = i4 - k * 24;
            *(float4*)&w_lds[k][j4 << 2] =
                *(const float4*)(W_off + (size_t)(kc + k) * 96 + (j4 << 2));
        }
        __syncthreads();
#pragma unroll 8
        for (int k = 0; k < 64; ++k) {
            float a = qcol[(size_t)(kc + k) * NPIX];   // coalesced global
#pragma unroll
            for (int j4 = 0; j4 < 6; ++j4) {
                float4 w = *(const float4*)&w_lds[k][j0 + (j4 << 2)]; // wave-broadcast
                acc[j4 * 4 + 0] = fmaf(a, w.x, acc[j4 * 4 + 0]);
                acc[j4 * 4 + 1] = fmaf(a, w.y, acc[j4 * 4 + 1]);
                acc[j4 * 4 + 2] = fmaf(a, w.z, acc[j4 * 4 + 2]);
                acc[j4 * 4 + 3] = fmaf(a, w.w, acc[j4 * 4 + 3]);
            }
        }
        __syncthreads();
    }

    const int n = n0 + px;
    const int x = n & 63;
    const int y = n >> 6;
    const float fx = (float)x, fy = (float)y;

#pragma unroll
    for (int hh = 0; hh < 2; ++hh) {
        const int head = jg * 2 + hh;
        const int lb   = hh * 12;
        float ox[4], oy[4], l[4];
#pragma unroll
        for (int p = 0; p < 4; ++p) {
            ox[p] = acc[lb + p * 3 + 0] + b_off[j0 + lb + p * 3 + 0];
            oy[p] = acc[lb + p * 3 + 1] + b_off[j0 + lb + p * 3 + 1];
            l[p]  = acc[lb + p * 3 + 2] + b_off[j0 + lb + p * 3 + 2];
        }
        float m = fmaxf(fmaxf(l[0], l[1]), fmaxf(l[2], l[3]));
        float e[4], s = 0.f;
#pragma unroll
        for (int p = 0; p < 4; ++p) { e[p] = __expf(l[p] - m); s += e[p]; }
        float inv = 1.f / s;
        float4* cp = coords + ((size_t)(b * NPIX + n) * NH + head) * NPTS;
#pragma unroll
        for (int p = 0; p < 4; ++p) {
            cp[p] = make_float4(fx + ox[p] * 3.15f, fy + oy[p] * 3.15f, e[p] * inv, 0.f);
        }
    }
}

// ---------------------------------------------------------------------------
// Kernel T: transpose key [b][c][n] -> keyT [b][n][c]  (channel-last)
// ---------------------------------------------------------------------------
__global__ __launch_bounds__(256)
void kT_transpose(const float* __restrict__ key, float* __restrict__ keyT)
{
    __shared__ float tile[64][65];
    int bid = blockIdx.x;                  // B*4*64 = 2048
    const int nt = bid & 63; bid >>= 6;
    const int ct = bid & 3;  bid >>= 2;
    const int b  = bid;
    const int n0 = nt * 64, c0 = ct * 64;
    const int t = threadIdx.x;

    const float* src = key + ((size_t)b * CCH + c0) * NPIX + n0;
#pragma unroll
    for (int ii = 0; ii < 4; ++ii) {
        int idx = t + ii * 256;
        int cc = idx >> 4, q = idx & 15;
        float4 v = *(const float4*)(src + (size_t)cc * NPIX + (q << 2));
        tile[cc][(q << 2) + 0] = v.x;
        tile[cc][(q << 2) + 1] = v.y;
        tile[cc][(q << 2) + 2] = v.z;
        tile[cc][(q << 2) + 3] = v.w;
    }
    __syncthreads();
    float* dst = keyT + ((size_t)(b * NPIX + n0)) * CCH + c0;
#pragma unroll
    for (int ii = 0; ii < 4; ++ii) {
        int idx = t + ii * 256;
        int nn = idx >> 4, q = idx & 15;
        float4 v = make_float4(tile[(q << 2) + 0][nn], tile[(q << 2) + 1][nn],
                               tile[(q << 2) + 2][nn], tile[(q << 2) + 3][nn]);
        *(float4*)(dst + (size_t)nn * CCH + (q << 2)) = v;
    }
}

// ---------------------------------------------------------------------------
// Kernel B: channel-last gather.  Wave = 1 pixel x 8 heads; lanegroup of
// 8 lanes per head, each lane owns 4 channels (float4).  No LDS, no sync.
// ---------------------------------------------------------------------------
__global__ __launch_bounds__(256)
void kB_gather(const float* __restrict__ keyT, const float4* __restrict__ coords,
               float* __restrict__ feat)
{
    const int bid  = blockIdx.x;
    const int sbid = (bid & 7) * 1024 + (bid >> 3);   // XCD-chunked swizzle

    const int t  = threadIdx.x;
    const int wv = t >> 6, l = t & 63;
    const int g  = sbid * 4 + wv;          // global pixel id, 0..32767
    const int b  = g >> 12;
    const int head = l >> 3;
    const int cl   = (l & 7) << 2;
    const int c    = head * DH + cl;

    const float*  kb = keyT + (((size_t)b << 12)) * CCH;
    const float4* cp = coords + ((size_t)g * NH + head) * NPTS;

    float4 acc = make_float4(0.f, 0.f, 0.f, 0.f);
#pragma unroll
    for (int pt = 0; pt < 4; ++pt) {
        float4 co = cp[pt];
        float xp = co.x, yp = co.y, wgt = co.z;
        float x0f = floorf(xp), y0f = floorf(yp);
        int   x0  = (int)x0f,  y0  = (int)y0f;
        float wx  = xp - x0f,  wy  = yp - y0f;
#pragma unroll
        for (int cr = 0; cr < 4; ++cr) {
            int   xi = x0 + (cr & 1);
            int   yi = y0 + (cr >> 1);
            float wc = ((cr & 1) ? wx : 1.f - wx) * ((cr >> 1) ? wy : 1.f - wy);
            bool  valid = (xi >= 0) && (xi < WW) && (yi >= 0) && (yi < HH);
            int   xc = min(max(xi, 0), WW - 1);
            int   yc = min(max(yi, 0), HH - 1);
            float ww = valid ? (wgt * wc) : 0.f;
            float4 v = *(const float4*)(kb + ((size_t)((yc << 6) + xc)) * CCH + c);
            acc.x = fmaf(ww, v.x, acc.x);
            acc.y = fmaf(ww, v.y, acc.y);
            acc.z = fmaf(ww, v.z, acc.z);
            acc.w = fmaf(ww, v.w, acc.w);
        }
    }
    *(float4*)(feat + (size_t)g * CCH + c) = acc;
}

// ---------------------------------------------------------------------------
// Kernel B (fallback, round-1 proven): scalar strided gather from original key
// ---------------------------------------------------------------------------
__global__ __launch_bounds__(256)
void kB_sample(const float* __restrict__ key, const float4* __restrict__ coords,
               float* __restrict__ feat)
{
    __shared__ float cx[4][64], cy[4][64], cw[4][64];

    const int t = threadIdx.x;
    int bi = blockIdx.x;
    const int y    = bi & 63; bi >>= 6;
    const int head = bi & 7;  bi >>= 3;
    const int b    = bi;

    {
        const int xx = t >> 2, pt = t & 3;
        float4 v = coords[((size_t)(b * NPIX + y * WW + xx) * NH + head) * NPTS + pt];
        cx[pt][xx] = v.x; cy[pt][xx] = v.y; cw[pt][xx] = v.z;
    }
    __syncthreads();

    const int x  = t & 63;
    const int cg = t >> 6;
    const int c0 = head * DH + cg * 8;
    const float* kbase = key + ((size_t)b * CCH + c0) * NPIX;

    float acc[8];
#pragma unroll
    for (int i = 0; i < 8; ++i) acc[i] = 0.f;

#pragma unroll
    for (int pt = 0; pt < 4; ++pt) {
        float xp = cx[pt][x], yp = cy[pt][x], wgt = cw[pt][x];
        float x0f = floorf(xp), y0f = floorf(yp);
        int   x0  = (int)x0f,  y0  = (int)y0f;
        float wx  = xp - x0f,  wy  = yp - y0f;
#pragma unroll
        for (int cr = 0; cr < 4; ++cr) {
            int   xi = x0 + (cr & 1);
            int   yi = y0 + (cr >> 1);
            float wc = ((cr & 1) ? wx : 1.f - wx) * ((cr >> 1) ? wy : 1.f - wy);
            bool  valid = (xi >= 0) && (xi < WW) && (yi >= 0) && (yi < HH);
            int   xc = min(max(xi, 0), WW - 1);
            int   yc = min(max(yi, 0), HH - 1);
            const float* p = kbase + yc * WW + xc;
            float ww = valid ? (wgt * wc) : 0.f;
#pragma unroll
            for (int c = 0; c < 8; ++c)
                acc[c] = fmaf(ww, p[(size_t)c * NPIX], acc[c]);
        }
    }

    float* fp = feat + (size_t)(b * NPIX + y * WW + x) * CCH + c0;
    *(float4*)fp       = make_float4(acc[0], acc[1], acc[2], acc[3]);
    *(float4*)(fp + 4) = make_float4(acc[4], acc[5], acc[6], acc[7]);
}

// ---------------------------------------------------------------------------
// Kernel C: out = feat @ W_proj + b_proj.  128x128 tile, 8x8 per thread,
// BK=32.  a_lds padded to 132 floats/row: transposed stores 4-way (not
// 8-way), rows stay 16B-aligned for ds_read_b128.  Global->reg prefetch
// issues next chunk's loads while current chunk's FMAs drain.
// ---------------------------------------------------------------------------
__global__ __launch_bounds__(256)
void kC_proj(const float* __restrict__ feat, const float* __restrict__ W_proj,
             const float* __restrict__ b_proj, float* __restrict__ out)
{
    __shared__ float a_lds[32][132];   // [k][m], pad 4
    __shared__ float b_lds[32][128];   // [k][n]

    const int t  = threadIdx.x;
    const int mb = blockIdx.x >> 1;    // 256 m-tiles
    const int nb = blockIdx.x & 1;     // 2 n-tiles
    const int m0 = mb * 128, n0 = nb * 128;

    const int tm = t >> 4, tn = t & 15;
    const int ra = t >> 3, qa = t & 7;    // A loader: row, k-quad
    const int kb = t >> 5, qb = t & 31;   // B loader: k, n-quad

    float acc[8][8];
#pragma unroll
    for (int i = 0; i < 8; ++i)
#pragma unroll
        for (int j = 0; j < 8; ++j) acc[i][j] = 0.f;

    for (int kc = 0; kc < 256; kc += 32) {
        // A: 128 rows x 8 k-quads = 1024 float4 / 256 thr = 4 each
        float4 a[4];
#pragma unroll
        for (int ii = 0; ii < 4; ++ii)
            a[ii] = *(const float4*)(feat + (size_t)(m0 + ra + ii * 32) * 256 + kc + (qa << 2));
        // B: 32 k x 32 n-quads = 1024 float4 / 256 thr = 4 each
        float4 w[4];
#pragma unroll
        for (int ii = 0; ii < 4; ++ii)
            w[ii] = *(const float4*)(W_proj + (size_t)(kc + kb + ii * 8) * 256 + n0 + (qb << 2));
        __syncthreads();   // previous chunk fully consumed
#pragma unroll
        for (int ii = 0; ii < 4; ++ii) {
            const int r = ra + ii * 32;
            a_lds[(qa << 2) + 0][r] = a[ii].x;
            a_lds[(qa << 2) + 1][r] = a[ii].y;
            a_lds[(qa << 2) + 2][r] = a[ii].z;
            a_lds[(qa << 2) + 3][r] = a[ii].w;
        }
#pragma unroll
        for (int ii = 0; ii < 4; ++ii)
            *(float4*)&b_lds[kb + ii * 8][qb << 2] = w[ii];
        __syncthreads();
#pragma unroll
        for (int k = 0; k < 32; ++k) {
            float4 av0 = *(const float4*)&a_lds[k][tm << 2];        // broadcast x16
            float4 av1 = *(const float4*)&a_lds[k][64 + (tm << 2)];
            float4 bv0 = *(const float4*)&b_lds[k][tn << 2];        // 2-way
            float4 bv1 = *(const float4*)&b_lds[k][64 + (tn << 2)];
            float ar[8] = {av0.x, av0.y, av0.z, av0.w, av1.x, av1.y, av1.z, av1.w};
            float br[8] = {bv0.x, bv0.y, bv0.z, bv0.w, bv1.x, bv1.y, bv1.z, bv1.w};
#pragma unroll
            for (int i = 0; i < 8; ++i)
#pragma unroll
                for (int j = 0; j < 8; ++j)
                    acc[i][j] = fmaf(ar[i], br[j], acc[i][j]);
        }
    }

    const float4 bp0 = *(const float4*)(b_proj + n0 + (tn << 2));
    const float4 bp1 = *(const float4*)(b_proj + n0 + 64 + (tn << 2));
    const float bpr[8] = {bp0.x, bp0.y, bp0.z, bp0.w, bp1.x, bp1.y, bp1.z, bp1.w};
#pragma unroll
    for (int i = 0; i < 8; ++i) {
        const int m = m0 + ((i < 4) ? 0 : 64) + (tm << 2) + (i & 3);
        float* op = out + (size_t)m * 256 + n0;
        *(float4*)(op + (tn << 2)) =
            make_float4(acc[i][0] + bpr[0], acc[i][1] + bpr[1],
                        acc[i][2] + bpr[2], acc[i][3] + bpr[3]);
        *(float4*)(op + 64 + (tn << 2)) =
            make_float4(acc[i][4] + bpr[4], acc[i][5] + bpr[5],
                        acc[i][6] + bpr[6], acc[i][7] + bpr[7]);
    }
}

// ---------------------------------------------------------------------------
extern "C" void kernel_launch(void* const* d_in, const int* in_sizes, int n_in,
                              void* d_out, int out_size, void* d_ws, size_t ws_size,
                              hipStream_t stream)
{
    const float* query  = (const float*)d_in[0];
    const float* key    = (const float*)d_in[1];
    const float* W_off  = (const float*)d_in[2];
    const float* b_off  = (const float*)d_in[3];
    const float* W_proj = (const float*)d_in[4];
    const float* b_proj = (const float*)d_in[5];
    float* out = (float*)d_out;

    const size_t keyT_bytes   = (size_t)BB * NPIX * CCH * sizeof(float);          // 33.55 MB
    const size_t coords_bytes = (size_t)BB * NPIX * NH * NPTS * sizeof(float4);   // 16.78 MB
    const size_t feat_bytes   = (size_t)BB * NPIX * CCH * sizeof(float);          // 33.55 MB

    if (ws_size >= keyT_bytes + coords_bytes + feat_bytes) {
        float*  keyT   = (float*)d_ws;
        float4* coords = (float4*)((char*)d_ws + keyT_bytes);
        float*  feat   = (float*)((char*)d_ws + keyT_bytes + coords_bytes);

        kA_offsets<<<(BB * NPIX) / 64, 256, 0, stream>>>(query, W_off, b_off, coords);
        kT_transpose<<<BB * 4 * 64, 256, 0, stream>>>(key, keyT);
        kB_gather<<<(BB * NPIX) / 4, 256, 0, stream>>>(keyT, coords, feat);
        kC_proj<<<(BB * NPIX / 128) * 2, 256, 0, stream>>>(feat, W_proj, b_proj, out);
    } else {
        // fallback: round-1 proven path (needs 50.3 MB)
        float4* coords = (float4*)d_ws;
        float*  feat   = (float*)((char*)d_ws + coords_bytes);

        kA_offsets<<<(BB * NPIX) / 64, 256, 0, stream>>>(query, W_off, b_off, coords);
        kB_sample<<<BB * NH * HH, 256, 0, stream>>>(key, coords, feat);
        kC_proj<<<(BB * NPIX / 128) * 2, 256, 0, stream>>>(feat, W_proj, b_proj, out);
    }
}

// Round 4
// 246.842 us; speedup vs baseline: 1.1251x; 1.1251x over previous
//
#include <hip/hip_runtime.h>

#define NH   8
#define NPTS 4
#define BB   8
#define CCH  256
#define HH   64
#define WW   64
#define NPIX 4096   // H*W
#define DH   32     // C/NH

// ---------------------------------------------------------------------------
// Kernel A: coords = softmax-epilogue( query^T @ W_off + b_off ).
// GEMM M=32768, J=96 (=whole width), K=256.  Tile 128x96, BK=64, 256 thr,
// per-thread 4m x 12j (12j = one head = 4 points -> softmax in-register).
// query is k-major => A-tile stages with NO transpose (conflict-free).
// w_lds padded 96->100 to kill the 96 % 32 == 0 staging alias.
// ---------------------------------------------------------------------------
__global__ __launch_bounds__(256)
void kA_gemm(const float* __restrict__ query, const float* __restrict__ W_off,
             const float* __restrict__ b_off, float4* __restrict__ coords)
{
    __shared__ float a_lds[64][128];   // [k][m]
    __shared__ float w_lds[64][100];   // [k][j], pad 4

    const int t  = threadIdx.x;
    const int m0 = blockIdx.x * 128;       // global pixel base (b*NPIX + n)
    const int b  = m0 >> 12;
    const int n0 = m0 & (NPIX - 1);
    const float* qbase = query + (size_t)b * CCH * NPIX + n0;

    const int tm = t >> 3;    // 0..31 -> rows 4*tm..4*tm+3
    const int tj = t & 7;     // head, j-block tj*12..tj*12+11

    float acc[4][12];
#pragma unroll
    for (int i = 0; i < 4; ++i)
#pragma unroll
        for (int j = 0; j < 12; ++j) acc[i][j] = 0.f;

    for (int kc = 0; kc < CCH; kc += 64) {
        // A: 64 k x 128 m = 2048 float4 / 256 thr = 8 each (coalesced rows)
        float4 a[8];
#pragma unroll
        for (int ii = 0; ii < 8; ++ii) {
            const int idx = t + ii * 256;
            a[ii] = *(const float4*)(qbase + (size_t)(kc + (idx >> 5)) * NPIX
                                     + ((idx & 31) << 2));
        }
        // W: 64 k x 96 j = 1536 float4 / 256 thr = 6 each
        float4 w[6];
#pragma unroll
        for (int ii = 0; ii < 6; ++ii) {
            const int idx = t + ii * 256;
            const int kk = idx / 24, q = idx - kk * 24;
            w[ii] = *(const float4*)(W_off + (size_t)(kc + kk) * 96 + (q << 2));
        }
        __syncthreads();   // previous chunk fully consumed
#pragma unroll
        for (int ii = 0; ii < 8; ++ii) {
            const int idx = t + ii * 256;
            *(float4*)&a_lds[idx >> 5][(idx & 31) << 2] = a[ii];
        }
#pragma unroll
        for (int ii = 0; ii < 6; ++ii) {
            const int idx = t + ii * 256;
            const int kk = idx / 24, q = idx - kk * 24;
            *(float4*)&w_lds[kk][q << 2] = w[ii];
        }
        __syncthreads();
#pragma unroll 16
        for (int k = 0; k < 64; ++k) {
            const float4 av = *(const float4*)&a_lds[k][tm << 2];
            const float4 w0 = *(const float4*)&w_lds[k][tj * 12];
            const float4 w1 = *(const float4*)&w_lds[k][tj * 12 + 4];
            const float4 w2 = *(const float4*)&w_lds[k][tj * 12 + 8];
            const float ar[4] = {av.x, av.y, av.z, av.w};
            const float wr[12] = {w0.x, w0.y, w0.z, w0.w,
                                  w1.x, w1.y, w1.z, w1.w,
                                  w2.x, w2.y, w2.z, w2.w};
#pragma unroll
            for (int i = 0; i < 4; ++i)
#pragma unroll
                for (int j = 0; j < 12; ++j)
                    acc[i][j] = fmaf(ar[i], wr[j], acc[i][j]);
        }
    }

    // epilogue: bias + softmax over 4 points, emit coords
    float bo[12];
#pragma unroll
    for (int j = 0; j < 12; ++j) bo[j] = b_off[tj * 12 + j];

#pragma unroll
    for (int i = 0; i < 4; ++i) {
        const int g = m0 + (tm << 2) + i;       // global pixel id
        const int n = g & (NPIX - 1);
        const float fx = (float)(n & 63), fy = (float)(n >> 6);

        float ox[4], oy[4], l[4];
#pragma unroll
        for (int p = 0; p < 4; ++p) {
            ox[p] = acc[i][p * 3 + 0] + bo[p * 3 + 0];
            oy[p] = acc[i][p * 3 + 1] + bo[p * 3 + 1];
            l[p]  = acc[i][p * 3 + 2] + bo[p * 3 + 2];
        }
        float m = fmaxf(fmaxf(l[0], l[1]), fmaxf(l[2], l[3]));
        float e[4], s = 0.f;
#pragma unroll
        for (int p = 0; p < 4; ++p) { e[p] = __expf(l[p] - m); s += e[p]; }
        const float inv = 1.f / s;

        float4* cp = coords + ((size_t)g * NH + tj) * NPTS;
#pragma unroll
        for (int p = 0; p < 4; ++p)
            cp[p] = make_float4(fx + ox[p] * 3.15f, fy + oy[p] * 3.15f,
                                e[p] * inv, 0.f);
    }
}

// ---------------------------------------------------------------------------
// Kernel T: transpose key [b][c][n] -> keyT [b][n][c]  (channel-last)
// ---------------------------------------------------------------------------
__global__ __launch_bounds__(256)
void kT_transpose(const float* __restrict__ key, float* __restrict__ keyT)
{
    __shared__ float tile[64][65];
    int bid = blockIdx.x;                  // B*4*64 = 2048
    const int nt = bid & 63; bid >>= 6;
    const int ct = bid & 3;  bid >>= 2;
    const int b  = bid;
    const int n0 = nt * 64, c0 = ct * 64;
    const int t = threadIdx.x;

    const float* src = key + ((size_t)b * CCH + c0) * NPIX + n0;
#pragma unroll
    for (int ii = 0; ii < 4; ++ii) {
        int idx = t + ii * 256;
        int cc = idx >> 4, q = idx & 15;
        float4 v = *(const float4*)(src + (size_t)cc * NPIX + (q << 2));
        tile[cc][(q << 2) + 0] = v.x;
        tile[cc][(q << 2) + 1] = v.y;
        tile[cc][(q << 2) + 2] = v.z;
        tile[cc][(q << 2) + 3] = v.w;
    }
    __syncthreads();
    float* dst = keyT + ((size_t)(b * NPIX + n0)) * CCH + c0;
#pragma unroll
    for (int ii = 0; ii < 4; ++ii) {
        int idx = t + ii * 256;
        int nn = idx >> 4, q = idx & 15;
        float4 v = make_float4(tile[(q << 2) + 0][nn], tile[(q << 2) + 1][nn],
                               tile[(q << 2) + 2][nn], tile[(q << 2) + 3][nn]);
        *(float4*)(dst + (size_t)nn * CCH + (q << 2)) = v;
    }
}

// ---------------------------------------------------------------------------
// Kernel B: channel-last gather.  Wave = 1 pixel x 8 heads; lanegroup of
// 8 lanes per head, each lane owns 4 channels (float4).  No LDS, no sync.
// XCD-chunked swizzle: XCD i sees only batch i -> 4 MB keyT slice L2-resident.
// ---------------------------------------------------------------------------
__global__ __launch_bounds__(256)
void kB_gather(const float* __restrict__ keyT, const float4* __restrict__ coords,
               float* __restrict__ feat)
{
    const int bid  = blockIdx.x;
    const int sbid = (bid & 7) * 1024 + (bid >> 3);

    const int t  = threadIdx.x;
    const int wv = t >> 6, l = t & 63;
    const int g  = sbid * 4 + wv;          // global pixel id, 0..32767
    const int b  = g >> 12;
    const int head = l >> 3;
    const int cl   = (l & 7) << 2;
    const int c    = head * DH + cl;

    const float*  kb = keyT + (((size_t)b << 12)) * CCH;
    const float4* cp = coords + ((size_t)g * NH + head) * NPTS;

    float4 acc = make_float4(0.f, 0.f, 0.f, 0.f);
#pragma unroll
    for (int pt = 0; pt < 4; ++pt) {
        float4 co = cp[pt];
        float xp = co.x, yp = co.y, wgt = co.z;
        float x0f = floorf(xp), y0f = floorf(yp);
        int   x0  = (int)x0f,  y0  = (int)y0f;
        float wx  = xp - x0f,  wy  = yp - y0f;
#pragma unroll
        for (int cr = 0; cr < 4; ++cr) {
            int   xi = x0 + (cr & 1);
            int   yi = y0 + (cr >> 1);
            float wc = ((cr & 1) ? wx : 1.f - wx) * ((cr >> 1) ? wy : 1.f - wy);
            bool  valid = (xi >= 0) && (xi < WW) && (yi >= 0) && (yi < HH);
            int   xc = min(max(xi, 0), WW - 1);
            int   yc = min(max(yi, 0), HH - 1);
            float ww = valid ? (wgt * wc) : 0.f;
            float4 v = *(const float4*)(kb + ((size_t)((yc << 6) + xc)) * CCH + c);
            acc.x = fmaf(ww, v.x, acc.x);
            acc.y = fmaf(ww, v.y, acc.y);
            acc.z = fmaf(ww, v.z, acc.z);
            acc.w = fmaf(ww, v.w, acc.w);
        }
    }
    *(float4*)(feat + (size_t)g * CCH + c) = acc;
}

// ---------------------------------------------------------------------------
// Kernel B (fallback): scalar strided gather from original key layout
// ---------------------------------------------------------------------------
__global__ __launch_bounds__(256)
void kB_sample(const float* __restrict__ key, const float4* __restrict__ coords,
               float* __restrict__ feat)
{
    __shared__ float cx[4][64], cy[4][64], cw[4][64];

    const int t = threadIdx.x;
    int bi = blockIdx.x;
    const int y    = bi & 63; bi >>= 6;
    const int head = bi & 7;  bi >>= 3;
    const int b    = bi;

    {
        const int xx = t >> 2, pt = t & 3;
        float4 v = coords[((size_t)(b * NPIX + y * WW + xx) * NH + head) * NPTS + pt];
        cx[pt][xx] = v.x; cy[pt][xx] = v.y; cw[pt][xx] = v.z;
    }
    __syncthreads();

    const int x  = t & 63;
    const int cg = t >> 6;
    const int c0 = head * DH + cg * 8;
    const float* kbase = key + ((size_t)b * CCH + c0) * NPIX;

    float acc[8];
#pragma unroll
    for (int i = 0; i < 8; ++i) acc[i] = 0.f;

#pragma unroll
    for (int pt = 0; pt < 4; ++pt) {
        float xp = cx[pt][x], yp = cy[pt][x], wgt = cw[pt][x];
        float x0f = floorf(xp), y0f = floorf(yp);
        int   x0  = (int)x0f,  y0  = (int)y0f;
        float wx  = xp - x0f,  wy  = yp - y0f;
#pragma unroll
        for (int cr = 0; cr < 4; ++cr) {
            int   xi = x0 + (cr & 1);
            int   yi = y0 + (cr >> 1);
            float wc = ((cr & 1) ? wx : 1.f - wx) * ((cr >> 1) ? wy : 1.f - wy);
            bool  valid = (xi >= 0) && (xi < WW) && (yi >= 0) && (yi < HH);
            int   xc = min(max(xi, 0), WW - 1);
            int   yc = min(max(yi, 0), HH - 1);
            const float* p = kbase + yc * WW + xc;
            float ww = valid ? (wgt * wc) : 0.f;
#pragma unroll
            for (int c = 0; c < 8; ++c)
                acc[c] = fmaf(ww, p[(size_t)c * NPIX], acc[c]);
        }
    }

    float* fp = feat + (size_t)(b * NPIX + y * WW + x) * CCH + c0;
    *(float4*)fp       = make_float4(acc[0], acc[1], acc[2], acc[3]);
    *(float4*)(fp + 4) = make_float4(acc[4], acc[5], acc[6], acc[7]);
}

// ---------------------------------------------------------------------------
// Kernel C: out = feat @ W_proj + b_proj.  128x128 tile, 8x8 per thread,
// BK=32, a_lds padded to 132.
// ---------------------------------------------------------------------------
__global__ __launch_bounds__(256)
void kC_proj(const float* __restrict__ feat, const float* __restrict__ W_proj,
             const float* __restrict__ b_proj, float* __restrict__ out)
{
    __shared__ float a_lds[32][132];   // [k][m], pad 4
    __shared__ float b_lds[32][128];   // [k][n]

    const int t  = threadIdx.x;
    const int mb = blockIdx.x >> 1;
    const int nb = blockIdx.x & 1;
    const int m0 = mb * 128, n0 = nb * 128;

    const int tm = t >> 4, tn = t & 15;
    const int ra = t >> 3, qa = t & 7;
    const int kb = t >> 5, qb = t & 31;

    float acc[8][8];
#pragma unroll
    for (int i = 0; i < 8; ++i)
#pragma unroll
        for (int j = 0; j < 8; ++j) acc[i][j] = 0.f;

    for (int kc = 0; kc < 256; kc += 32) {
        float4 a[4];
#pragma unroll
        for (int ii = 0; ii < 4; ++ii)
            a[ii] = *(const float4*)(feat + (size_t)(m0 + ra + ii * 32) * 256 + kc + (qa << 2));
        float4 w[4];
#pragma unroll
        for (int ii = 0; ii < 4; ++ii)
            w[ii] = *(const float4*)(W_proj + (size_t)(kc + kb + ii * 8) * 256 + n0 + (qb << 2));
        __syncthreads();
#pragma unroll
        for (int ii = 0; ii < 4; ++ii) {
            const int r = ra + ii * 32;
            a_lds[(qa << 2) + 0][r] = a[ii].x;
            a_lds[(qa << 2) + 1][r] = a[ii].y;
            a_lds[(qa << 2) + 2][r] = a[ii].z;
            a_lds[(qa << 2) + 3][r] = a[ii].w;
        }
#pragma unroll
        for (int ii = 0; ii < 4; ++ii)
            *(float4*)&b_lds[kb + ii * 8][qb << 2] = w[ii];
        __syncthreads();
#pragma unroll
        for (int k = 0; k < 32; ++k) {
            float4 av0 = *(const float4*)&a_lds[k][tm << 2];
            float4 av1 = *(const float4*)&a_lds[k][64 + (tm << 2)];
            float4 bv0 = *(const float4*)&b_lds[k][tn << 2];
            float4 bv1 = *(const float4*)&b_lds[k][64 + (tn << 2)];
            float ar[8] = {av0.x, av0.y, av0.z, av0.w, av1.x, av1.y, av1.z, av1.w};
            float br[8] = {bv0.x, bv0.y, bv0.z, bv0.w, bv1.x, bv1.y, bv1.z, bv1.w};
#pragma unroll
            for (int i = 0; i < 8; ++i)
#pragma unroll
                for (int j = 0; j < 8; ++j)
                    acc[i][j] = fmaf(ar[i], br[j], acc[i][j]);
        }
    }

    const float4 bp0 = *(const float4*)(b_proj + n0 + (tn << 2));
    const float4 bp1 = *(const float4*)(b_proj + n0 + 64 + (tn << 2));
    const float bpr[8] = {bp0.x, bp0.y, bp0.z, bp0.w, bp1.x, bp1.y, bp1.z, bp1.w};
#pragma unroll
    for (int i = 0; i < 8; ++i) {
        const int m = m0 + ((i < 4) ? 0 : 64) + (tm << 2) + (i & 3);
        float* op = out + (size_t)m * 256 + n0;
        *(float4*)(op + (tn << 2)) =
            make_float4(acc[i][0] + bpr[0], acc[i][1] + bpr[1],
                        acc[i][2] + bpr[2], acc[i][3] + bpr[3]);
        *(float4*)(op + 64 + (tn << 2)) =
            make_float4(acc[i][4] + bpr[4], acc[i][5] + bpr[5],
                        acc[i][6] + bpr[6], acc[i][7] + bpr[7]);
    }
}

// ---------------------------------------------------------------------------
extern "C" void kernel_launch(void* const* d_in, const int* in_sizes, int n_in,
                              void* d_out, int out_size, void* d_ws, size_t ws_size,
                              hipStream_t stream)
{
    const float* query  = (const float*)d_in[0];
    const float* key    = (const float*)d_in[1];
    const float* W_off  = (const float*)d_in[2];
    const float* b_off  = (const float*)d_in[3];
    const float* W_proj = (const float*)d_in[4];
    const float* b_proj = (const float*)d_in[5];
    float* out = (float*)d_out;

    const size_t keyT_bytes   = (size_t)BB * NPIX * CCH * sizeof(float);          // 33.55 MB
    const size_t coords_bytes = (size_t)BB * NPIX * NH * NPTS * sizeof(float4);   // 16.78 MB
    const size_t feat_bytes   = (size_t)BB * NPIX * CCH * sizeof(float);          // 33.55 MB

    if (ws_size >= keyT_bytes + coords_bytes + feat_bytes) {
        float*  keyT   = (float*)d_ws;
        float4* coords = (float4*)((char*)d_ws + keyT_bytes);
        float*  feat   = (float*)((char*)d_ws + keyT_bytes + coords_bytes);

        kA_gemm<<<(BB * NPIX) / 128, 256, 0, stream>>>(query, W_off, b_off, coords);
        kT_transpose<<<BB * 4 * 64, 256, 0, stream>>>(key, keyT);
        kB_gather<<<(BB * NPIX) / 4, 256, 0, stream>>>(keyT, coords, feat);
        kC_proj<<<(BB * NPIX / 128) * 2, 256, 0, stream>>>(feat, W_proj, b_proj, out);
    } else {
        // fallback path (needs 50.3 MB)
        float4* coords = (float4*)d_ws;
        float*  feat   = (float*)((char*)d_ws + coords_bytes);

        kA_gemm<<<(BB * NPIX) / 128, 256, 0, stream>>>(query, W_off, b_off, coords);
        kB_sample<<<BB * NH * HH, 256, 0, stream>>>(key, coords, feat);
        kC_proj<<<(BB * NPIX / 128) * 2, 256, 0, stream>>>(feat, W_proj, b_proj, out);
    }
}